// Round 2
// baseline (153.053 us; speedup 1.0000x reference)
//
#include <hip/hip_runtime.h>
#include <hip/hip_bf16.h>

// Problem constants
#define NUM_NODES 500000
#define DD  128
#define UU  32
#define TT  4
#define AA  32
#define NSRC 65536
#define BB  8192
#define EE  262144          // = 2^18
#define AGG_FLOATS (BB * TT * UU)   // 1,048,576 floats = 4 MB

// ---------------- Kernel 1: zero the aggregation workspace ----------------
__global__ __launch_bounds__(256) void zero_kernel(float4* __restrict__ p) {
    int i = blockIdx.x * 256 + threadIdx.x;   // grid covers AGG_FLOATS/4
    p[i] = make_float4(0.f, 0.f, 0.f, 0.f);
}

// ---------------- Kernel 2: edge scatter-aggregation ----------------------
// agg[dst][t][u] += node_type_embeddings[input_nodes[src]][t][u]
// 32 lanes per edge, one f32 atomic per element.
__global__ __launch_bounds__(256) void edge_kernel(
    const float* __restrict__ nte_in,            // [NUM_NODES][T*U] f32
    const int* __restrict__ input_nodes,         // [NSRC]
    const int* __restrict__ edge_src,            // [T*E]
    const int* __restrict__ edge_dst,            // [T*E]
    float* __restrict__ agg)                     // [B][T][U] f32
{
    int tid = blockIdx.x * 256 + threadIdx.x;
    int i = tid >> 5;            // edge linear index in [0, T*E)
    int u = tid & 31;
    int t = i >> 18;             // E = 2^18
    int src = edge_src[i];
    int dst = edge_dst[i];
    int node = input_nodes[src];
    float v = nte_in[node * (TT * UU) + t * UU + u];
    atomicAdd(&agg[dst * (TT * UU) + t * UU + u], v);
}

// ---------------- Kernel 3: per-output-node attention + transform ---------
// One wave (64 lanes) per output node b; 4 waves / block.
__global__ __launch_bounds__(256) void node_kernel(
    const float* __restrict__ node_emb,          // [NUM_NODES][D] f32
    const float* __restrict__ w,                 // [T][U][D] f32
    const float* __restrict__ s1,                // [T][U][A] f32
    const float* __restrict__ s2,                // [T][A] f32
    const int* __restrict__ output_nodes,        // [B]
    const float* __restrict__ agg,               // [B][T][U] f32
    float* __restrict__ out)                     // [B][T][D] f32
{
    __shared__ float s_nte[4][TT * UU];   // per-wave nte row (128 f32)
    __shared__ float s_sc[4][TT];
    __shared__ float s_comb[4][UU];

    int wave = threadIdx.x >> 6;
    int lane = threadIdx.x & 63;
    int b = blockIdx.x * 4 + wave;

    // load nte (128 floats) into LDS
    s_nte[wave][lane]      = agg[b * 128 + lane];
    s_nte[wave][lane + 64] = agg[b * 128 + lane + 64];
    __syncthreads();

    // h = tanh(nte . s1), scores = h . s2   (each lane: a = lane&31, two t's)
    int a  = lane & 31;
    int th = lane >> 5;               // 0 or 1
    float p0 = 0.f, p1 = 0.f;
    {
        int t0 = th, t1 = th + 2;
        float acc0 = 0.f, acc1 = 0.f;
        #pragma unroll
        for (int u = 0; u < UU; ++u) {
            acc0 += s_nte[wave][t0 * UU + u] * s1[(t0 * UU + u) * AA + a];
            acc1 += s_nte[wave][t1 * UU + u] * s1[(t1 * UU + u) * AA + a];
        }
        p0 = tanhf(acc0) * s2[t0 * AA + a];
        p1 = tanhf(acc1) * s2[t1 * AA + a];
    }
    // reduce over a (within each 32-lane half)
    #pragma unroll
    for (int m = 1; m < 32; m <<= 1) {
        p0 += __shfl_xor(p0, m, 64);
        p1 += __shfl_xor(p1, m, 64);
    }
    if ((lane & 31) == 0) { s_sc[wave][th] = p0; s_sc[wave][th + 2] = p1; }
    __syncthreads();

    // softmax over T=4 (redundant per lane)
    float sc0 = s_sc[wave][0], sc1 = s_sc[wave][1];
    float sc2 = s_sc[wave][2], sc3 = s_sc[wave][3];
    float mx = fmaxf(fmaxf(sc0, sc1), fmaxf(sc2, sc3));
    float e0 = expf(sc0 - mx), e1 = expf(sc1 - mx);
    float e2 = expf(sc2 - mx), e3 = expf(sc3 - mx);
    float isum = 1.f / (e0 + e1 + e2 + e3);
    float at0 = e0 * isum, at1 = e1 * isum, at2 = e2 * isum, at3 = e3 * isum;

    // combined[u] = sum_t att[t] * nte[t][u]
    if (lane < 32) {
        float c = at0 * s_nte[wave][a]
                + at1 * s_nte[wave][UU + a]
                + at2 * s_nte[wave][2 * UU + a]
                + at3 * s_nte[wave][3 * UU + a];
        s_comb[wave][a] = c;
    }
    __syncthreads();

    // trans[t][d] = sum_u combined[u] * w[t][u][d]; add node emb; normalize
    int node = output_nodes[b];
    float v[8];
    float sq[4] = {0.f, 0.f, 0.f, 0.f};
    #pragma unroll
    for (int i = 0; i < 8; ++i) {
        int t = i >> 1;
        int d = ((i & 1) << 6) + lane;
        float acc = node_emb[node * DD + d];
        #pragma unroll
        for (int u = 0; u < UU; ++u)
            acc += s_comb[wave][u] * w[(t * UU + u) * DD + d];
        v[i] = acc;
        sq[t] += acc * acc;
    }
    #pragma unroll
    for (int m = 1; m < 64; m <<= 1) {
        #pragma unroll
        for (int t = 0; t < 4; ++t)
            sq[t] += __shfl_xor(sq[t], m, 64);
    }
    float invn[4];
    #pragma unroll
    for (int t = 0; t < 4; ++t)
        invn[t] = 1.f / fmaxf(sqrtf(sq[t]), 1e-12f);
    #pragma unroll
    for (int i = 0; i < 8; ++i) {
        float o = v[i] * invn[i >> 1];
        out[b * (TT * DD) + i * 64 + lane] = o;
    }
}

extern "C" void kernel_launch(void* const* d_in, const int* in_sizes, int n_in,
                              void* d_out, int out_size, void* d_ws, size_t ws_size,
                              hipStream_t stream) {
    const float* node_emb = (const float*)d_in[0];
    const float* nte_in   = (const float*)d_in[1];
    const float* w        = (const float*)d_in[2];
    const float* s1       = (const float*)d_in[3];
    const float* s2       = (const float*)d_in[4];
    const int* input_nodes  = (const int*)d_in[5];
    const int* output_nodes = (const int*)d_in[6];
    const int* edge_src     = (const int*)d_in[7];
    const int* edge_dst     = (const int*)d_in[8];
    float* out = (float*)d_out;
    float* agg = (float*)d_ws;   // needs 4 MB

    // 1) zero agg: 1,048,576 floats = 262,144 float4
    zero_kernel<<<dim3(AGG_FLOATS / 4 / 256), dim3(256), 0, stream>>>((float4*)agg);

    // 2) edge aggregation: T*E edges * 32 lanes = 33,554,432 threads
    edge_kernel<<<dim3((TT * EE * 32) / 256), dim3(256), 0, stream>>>(
        nte_in, input_nodes, edge_src, edge_dst, agg);

    // 3) per-node compute: 4 nodes / block
    node_kernel<<<dim3(BB / 4), dim3(256), 0, stream>>>(
        node_emb, w, s1, s2, output_nodes, agg, out);
}